// Round 6
// baseline (398.211 us; speedup 1.0000x reference)
//
#include <hip/hip_runtime.h>

typedef __attribute__((ext_vector_type(8))) short short8;
typedef __attribute__((ext_vector_type(4))) short bfx4;
typedef __attribute__((ext_vector_type(4))) float floatx4;

#define N_NODES 20000
#define N_EDGES 160000
#define TILE_E 64
#define EBLK (N_EDGES / TILE_E)   // 2500

#define C0f   0.14433756729740643f   // sqrt(1/48)
#define C1f   0.21650635094610965f   // sqrt(3/64)
#define IS3   0.5773502691896258f    // 1/sqrt(3)
#define IS6   0.4082482904638631f    // 1/sqrt(6)
#define EPS_LN 1e-5f

// ws layout (bytes):
//   [0, 32768)        w1f: W1 bf16, MFMA B-frag order
//   [32768, 688128)   w2f: W2 bf16, MFMA B-frag order
//   [688128, 768128)  cnt: N_NODES floats (zeroed by prep)
#define W1F_OFF 0
#define W2F_OFF 32768
#define CNT_OFF 688128

#define XPAD 68   // transposed-array stride: 34 words -> <=4-way write conflict, 8B aligned

__device__ __forceinline__ short f2bf(float f) {   // fp32 -> bf16 RNE
    unsigned u = __float_as_uint(f);
    u += 0x7fff + ((u >> 16) & 1);
    return (short)(u >> 16);
}
__device__ __forceinline__ float bf2f(short s) {
    return __uint_as_float(((unsigned)(unsigned short)s) << 16);
}

__device__ __forceinline__ short8 load8_bf16(const float* p) {
    const float4* q = (const float4*)p;
    float4 f0 = q[0], f1 = q[1];
    short8 s;
    s[0]=f2bf(f0.x); s[1]=f2bf(f0.y); s[2]=f2bf(f0.z); s[3]=f2bf(f0.w);
    s[4]=f2bf(f1.x); s[5]=f2bf(f1.y); s[6]=f2bf(f1.z); s[7]=f2bf(f1.w);
    return s;
}

__device__ __forceinline__ floatx4 mfma4(const short8* a, short8 b0, short8 b1,
                                         short8 b2, short8 b3, float bias) {
    floatx4 C = {bias, bias, bias, bias};   // bias as C-init: free bias add
    C = __builtin_amdgcn_mfma_f32_16x16x32_bf16(a[0], b0, C, 0, 0, 0);
    C = __builtin_amdgcn_mfma_f32_16x16x32_bf16(a[1], b1, C, 0, 0, 0);
    C = __builtin_amdgcn_mfma_f32_16x16x32_bf16(a[2], b2, C, 0, 0, 0);
    C = __builtin_amdgcn_mfma_f32_16x16x32_bf16(a[3], b3, C, 0, 0, 0);
    return C;
}

// W1/W2 -> bf16 fragment order; also zero cnt.
__global__ __launch_bounds__(256)
void prep_kernel(const float* __restrict__ fc_w1, const float* __restrict__ fc_w2,
                 short* __restrict__ w1f, short* __restrict__ w2f,
                 float* __restrict__ cnt) {
    int g = blockIdx.x * 256 + threadIdx.x;
    if (g < N_NODES) cnt[g] = 0.0f;
    if (g < 2048) {                      // W1: t<8, kt<4
        int ln = g & 15, qd = (g >> 4) & 3, kt = (g >> 6) & 3, t = g >> 8;
        int n = t * 16 + ln, kb = kt * 32 + qd * 8;
        short8 s;
        #pragma unroll
        for (int j = 0; j < 8; ++j) s[j] = f2bf(fc_w1[(kb + j) * 128 + n]);
        *(short8*)(w1f + g * 8) = s;
        return;
    }
    int g2 = g - 2048;
    if (g2 < 40960) {                    // W2: t<160, kt<4
        int ln = g2 & 15, qd = (g2 >> 4) & 3, kt = (g2 >> 6) & 3, t = g2 >> 8;
        int n = t * 16 + ln, kb = kt * 32 + qd * 8;
        short8 s;
        #pragma unroll
        for (int j = 0; j < 8; ++j) s[j] = f2bf(fc_w2[(kb + j) * 2560 + n]);
        *(short8*)(w2f + g2 * 8) = s;
    }
}

__global__ __launch_bounds__(128, 4)
void edge_kernel(const float* __restrict__ node_attr,
                 const float* __restrict__ edge_attr,
                 const float* __restrict__ edge_sh,
                 const float* __restrict__ fc_b1,
                 const float* __restrict__ fc_b2,
                 const int*   __restrict__ edge_index,
                 const short* __restrict__ w1f,
                 const short* __restrict__ w2f,
                 float* __restrict__ accum,   // d_out, pre-zeroed
                 float* __restrict__ cnt)     // zeroed by prep
{
    // Union: s_H (hidden acts, 64x136 bf16 = 17408B) lives only between MLP1
    // and the A2-fragment read; the transposed x-arrays (13056B) then reuse
    // the same space. LDS total ~18.9KB -> 8 blocks/CU.
    __shared__ alignas(16) char s_mem[64 * 136 * 2];
    short* s_H    = (short*)s_mem;
    short* s_x0t  = (short*)s_mem;                          // [32][XPAD]
    short* s_x1t  = (short*)(s_mem + 2 * 32 * XPAD);        // [48][XPAD]
    short* s_x1dt = (short*)(s_mem + 2 * (32 + 48) * XPAD); // [16][XPAD]
    __shared__ float s_sh[64 * 4];
    __shared__ int   s_src[64];
    __shared__ int   s_dst[64];

    const int tid = threadIdx.x;
    const int e0  = blockIdx.x * TILE_E;

    // ---- A1: indices, sh ----
    if (tid < 64) {
        int s = edge_index[e0 + tid];
        int d = edge_index[N_EDGES + e0 + tid];
        s_src[tid] = s; s_dst[tid] = d;
        atomicAdd(&cnt[s], 1.0f);
    }
    s_sh[tid]       = edge_sh[(size_t)e0 * 4 + tid];
    s_sh[tid + 128] = edge_sh[(size_t)e0 * 4 + tid + 128];

    // ---- per-wave identity: wave owns 32 edges as 2 MFMA groups ----
    const int lane = tid & 63;
    const int wv   = tid >> 6;
    const int ln   = lane & 15;
    const int qd   = lane >> 4;
    const int eb0  = wv * 32 + qd * 4;        // group 0 C-row base
    const int eb1  = eb0 + 16;                // group 1

    // ---- MLP1: h = relu(EA @ W1 + b1) via MFMA; s_H rows are wave-private
    //      (wave wv writes/reads only rows [wv*32, wv*32+32)) -> no barrier.
    {
        short8 a1[2][4];
        #pragma unroll
        for (int g = 0; g < 2; ++g) {
            const float* ap = edge_attr + (size_t)(e0 + wv*32 + g*16 + ln) * 128 + qd * 8;
            #pragma unroll
            for (int kt = 0; kt < 4; ++kt) a1[g][kt] = load8_bf16(ap + kt * 32);
        }
        #pragma unroll
        for (int t = 0; t < 8; ++t) {
            const short* bp = w1f + t * 2048 + lane * 8;
            short8 b0 = *(const short8*)bp;
            short8 b1 = *(const short8*)(bp + 512);
            short8 b2 = *(const short8*)(bp + 1024);
            short8 b3 = *(const short8*)(bp + 1536);
            float bias = fc_b1[t * 16 + ln];
            #pragma unroll
            for (int g = 0; g < 2; ++g) {
                floatx4 C = mfma4(a1[g], b0, b1, b2, b3, bias);
                #pragma unroll
                for (int r = 0; r < 4; ++r)
                    s_H[(wv*32 + g*16 + qd*4 + r) * 136 + t*16 + ln] = f2bf(fmaxf(C[r], 0.f));
            }
        }
    }

    // A2 fragments (live across the whole main loop) — same-wave rows only
    short8 a2[2][4];
    #pragma unroll
    for (int g = 0; g < 2; ++g) {
        const short* hp = s_H + (wv*32 + g*16 + ln) * 136 + qd * 8;
        #pragma unroll
        for (int kt = 0; kt < 4; ++kt) a2[g][kt] = *(const short8*)(hp + kt * 32);
    }
    __syncthreads();   // all waves done with s_H; A1 data visible to all

    // ---- gather x (transposed bf16) into the union space + x1.sh1 dot ----
    #pragma unroll
    for (int i = 0; i < 40; ++i) {
        int f = tid + i * 128;
        int e = f / 80, c = f % 80;
        float v = node_attr[(size_t)s_dst[e] * 80 + c];
        if (c < 32) s_x0t[c * XPAD + e] = f2bf(v);
        else        s_x1t[(c - 32) * XPAD + e] = f2bf(v);
    }
    #pragma unroll
    for (int i = 0; i < 8; ++i) {
        int it = tid + i * 128;
        int e = it >> 4, u = it & 15;
        const float* xp = node_attr + (size_t)s_dst[e] * 80 + 32 + u * 3;
        float d = xp[0] * s_sh[e*4+1] + xp[1] * s_sh[e*4+2] + xp[2] * s_sh[e*4+3];
        s_x1dt[u * XPAD + e] = f2bf(d);
    }
    __syncthreads();

    const short* wbase = w2f + lane * 8;

    // ================= PHASE 1: out0 (regions 1-2) =================
    float r0lo[2][4] = {}, r0hi[2][4] = {}, r1lo[2][4] = {}, r1hi[2][4] = {};

    #pragma unroll 2
    for (int u = 0; u < 32; ++u) {       // region 1: tiles 2u, 2u+1
        const short* bp = wbase + (size_t)(2*u) * 2048;
        short8 L0 = *(const short8*)bp,          L1 = *(const short8*)(bp + 512);
        short8 L2 = *(const short8*)(bp + 1024), L3 = *(const short8*)(bp + 1536);
        short8 H0 = *(const short8*)(bp + 2048), H1 = *(const short8*)(bp + 2560);
        short8 H2 = *(const short8*)(bp + 3072), H3 = *(const short8*)(bp + 3584);
        float blo = fc_b2[2*u*16 + ln], bhi = fc_b2[2*u*16 + 16 + ln];
        #pragma unroll
        for (int g = 0; g < 2; ++g) {
            floatx4 Clo = mfma4(a2[g], L0, L1, L2, L3, blo);
            floatx4 Chi = mfma4(a2[g], H0, H1, H2, H3, bhi);
            bfx4 xs = *(const bfx4*)(s_x0t + u*XPAD + (g ? eb1 : eb0));
            #pragma unroll
            for (int r = 0; r < 4; ++r) {
                float a = bf2f(xs[r]);
                r0lo[g][r] += a * Clo[r];
                r0hi[g][r] += a * Chi[r];
            }
        }
    }
    #pragma unroll 2
    for (int u = 0; u < 16; ++u) {       // region 2: tiles 64+2u, 65+2u
        const short* bp = wbase + (size_t)(64 + 2*u) * 2048;
        short8 L0 = *(const short8*)bp,          L1 = *(const short8*)(bp + 512);
        short8 L2 = *(const short8*)(bp + 1024), L3 = *(const short8*)(bp + 1536);
        short8 H0 = *(const short8*)(bp + 2048), H1 = *(const short8*)(bp + 2560);
        short8 H2 = *(const short8*)(bp + 3072), H3 = *(const short8*)(bp + 3584);
        float blo = fc_b2[(64 + 2*u)*16 + ln], bhi = fc_b2[(64 + 2*u)*16 + 16 + ln];
        #pragma unroll
        for (int g = 0; g < 2; ++g) {
            floatx4 Clo = mfma4(a2[g], L0, L1, L2, L3, blo);
            floatx4 Chi = mfma4(a2[g], H0, H1, H2, H3, bhi);
            bfx4 xs = *(const bfx4*)(s_x1dt + u*XPAD + (g ? eb1 : eb0));
            #pragma unroll
            for (int r = 0; r < 4; ++r) {
                float a = bf2f(xs[r]);
                r1lo[g][r] += a * Clo[r];
                r1hi[g][r] += a * Chi[r];
            }
        }
    }
    // phase-1 epilogue: out0 scatter
    #pragma unroll
    for (int g = 0; g < 2; ++g)
        #pragma unroll
        for (int r = 0; r < 4; ++r) {
            int e = (g ? eb1 : eb0) + r;
            float sh0 = s_sh[e*4];
            int base = s_src[e] * 80;
            atomicAdd(&accum[base + ln],      C0f * (sh0 * r0lo[g][r] + IS3 * r1lo[g][r]));
            atomicAdd(&accum[base + 16 + ln], C0f * (sh0 * r0hi[g][r] + IS3 * r1hi[g][r]));
        }

    // ================= PHASE 2: out1 (regions 3-5) =================
    float r3[2][4] = {};
    float r4[2][4][3] = {};
    float r5[2][4][3] = {};

    #pragma unroll 2
    for (int u = 0; u < 32; ++u) {       // region 3: tile 96+u
        const short* bp = wbase + (size_t)(96 + u) * 2048;
        short8 b0 = *(const short8*)bp,          b1 = *(const short8*)(bp + 512);
        short8 b2 = *(const short8*)(bp + 1024), b3 = *(const short8*)(bp + 1536);
        float bias = fc_b2[(96 + u)*16 + ln];
        #pragma unroll
        for (int g = 0; g < 2; ++g) {
            floatx4 C = mfma4(a2[g], b0, b1, b2, b3, bias);
            bfx4 xs = *(const bfx4*)(s_x0t + u*XPAD + (g ? eb1 : eb0));
            #pragma unroll
            for (int r = 0; r < 4; ++r)
                r3[g][r] += bf2f(xs[r]) * C[r];
        }
    }
    for (int u = 0; u < 16; ++u) {       // regions 4+5: tiles 128+u, 144+u share x1 reads
        const short* bp4 = wbase + (size_t)(128 + u) * 2048;
        short8 F0 = *(const short8*)bp4,          F1 = *(const short8*)(bp4 + 512);
        short8 F2 = *(const short8*)(bp4 + 1024), F3 = *(const short8*)(bp4 + 1536);
        const short* bp5 = wbase + (size_t)(144 + u) * 2048;
        short8 G0 = *(const short8*)bp5,          G1 = *(const short8*)(bp5 + 512);
        short8 G2 = *(const short8*)(bp5 + 1024), G3 = *(const short8*)(bp5 + 1536);
        float b4 = fc_b2[(128 + u)*16 + ln], b5 = fc_b2[(144 + u)*16 + ln];
        #pragma unroll
        for (int g = 0; g < 2; ++g) {
            floatx4 C4 = mfma4(a2[g], F0, F1, F2, F3, b4);
            floatx4 C5 = mfma4(a2[g], G0, G1, G2, G3, b5);
            int eb = (g ? eb1 : eb0);
            bfx4 x0s = *(const bfx4*)(s_x1t + (u*3 + 0)*XPAD + eb);
            bfx4 x1s = *(const bfx4*)(s_x1t + (u*3 + 1)*XPAD + eb);
            bfx4 x2s = *(const bfx4*)(s_x1t + (u*3 + 2)*XPAD + eb);
            #pragma unroll
            for (int r = 0; r < 4; ++r) {
                float a0 = bf2f(x0s[r]), a1 = bf2f(x1s[r]), a2v = bf2f(x2s[r]);
                r4[g][r][0] += a0 * C4[r];  r5[g][r][0] += a0 * C5[r];
                r4[g][r][1] += a1 * C4[r];  r5[g][r][1] += a1 * C5[r];
                r4[g][r][2] += a2v * C4[r]; r5[g][r][2] += a2v * C5[r];
            }
        }
    }
    // phase-2 epilogue: out1 scatter (region-5 cross applied here; linear in u)
    #pragma unroll
    for (int g = 0; g < 2; ++g)
        #pragma unroll
        for (int r = 0; r < 4; ++r) {
            int e = (g ? eb1 : eb0) + r;
            float sh0 = s_sh[e*4], sa = s_sh[e*4+1], sb = s_sh[e*4+2], sc = s_sh[e*4+3];
            int base = s_src[e] * 80;
            float t3 = C1f * IS3 * r3[g][r];
            float s0 = C1f * IS3 * sh0;
            float c6 = C1f * IS6;
            float v50 = r5[g][r][1] * sc - r5[g][r][2] * sb;
            float v51 = r5[g][r][2] * sa - r5[g][r][0] * sc;
            float v52 = r5[g][r][0] * sb - r5[g][r][1] * sa;
            atomicAdd(&accum[base + 32 + ln*3 + 0], sa * t3 + s0 * r4[g][r][0] + c6 * v50);
            atomicAdd(&accum[base + 32 + ln*3 + 1], sb * t3 + s0 * r4[g][r][1] + c6 * v51);
            atomicAdd(&accum[base + 32 + ln*3 + 2], sc * t3 + s0 * r4[g][r][2] + c6 * v52);
        }
}

// Per-node: mean-divide, residual, equivariant layernorm. In-place on d_out.
__global__ __launch_bounds__(256)
void node_kernel(const float* __restrict__ node_attr,
                 const float* __restrict__ mean_shift,
                 const float* __restrict__ aw,
                 const float* __restrict__ ab,
                 const float* __restrict__ cnt,
                 float* __restrict__ out)
{
    int n = blockIdx.x * blockDim.x + threadIdx.x;
    if (n >= N_NODES) return;
    float inv = 1.0f / fmaxf(cnt[n], 1.0f);
    size_t base = (size_t)n * 80;
    float v[80];
    const float4* o4 = (const float4*)(out + base);
    const float4* a4 = (const float4*)(node_attr + base);
    #pragma unroll
    for (int i = 0; i < 20; ++i) {
        float4 o = o4[i], a = a4[i];
        v[4*i+0] = o.x * inv + a.x;
        v[4*i+1] = o.y * inv + a.y;
        v[4*i+2] = o.z * inv + a.z;
        v[4*i+3] = o.w * inv + a.w;
    }

    float m0 = 0.f;
    #pragma unroll
    for (int u = 0; u < 32; ++u) m0 += v[u];
    m0 *= (1.0f / 32.0f);
    float n0 = 0.f;
    #pragma unroll
    for (int u = 0; u < 32; ++u) {
        float f = v[u] - m0 * mean_shift[u];
        v[u] = f;
        n0 += f * f;
    }
    n0 = rsqrtf(n0 * (1.0f / 32.0f) + EPS_LN);
    #pragma unroll
    for (int u = 0; u < 32; ++u) v[u] = v[u] * (n0 * aw[u]) + ab[u];

    float m1[3] = {0.f, 0.f, 0.f};
    #pragma unroll
    for (int u = 0; u < 16; ++u)
        #pragma unroll
        for (int i = 0; i < 3; ++i) m1[i] += v[32 + u*3 + i];
    #pragma unroll
    for (int i = 0; i < 3; ++i) m1[i] *= (1.0f / 16.0f);
    float n1 = 0.f;
    #pragma unroll
    for (int u = 0; u < 16; ++u)
        #pragma unroll
        for (int i = 0; i < 3; ++i) {
            float f = v[32 + u*3 + i] - m1[i] * mean_shift[32 + u];
            v[32 + u*3 + i] = f;
            n1 += f * f;
        }
    n1 = rsqrtf(n1 * (1.0f / 48.0f) + EPS_LN);
    #pragma unroll
    for (int u = 0; u < 16; ++u)
        #pragma unroll
        for (int i = 0; i < 3; ++i)
            v[32 + u*3 + i] *= (n1 * aw[32 + u]);

    float4* w4 = (float4*)(out + base);
    #pragma unroll
    for (int i = 0; i < 20; ++i) {
        float4 o; o.x = v[4*i]; o.y = v[4*i+1]; o.z = v[4*i+2]; o.w = v[4*i+3];
        w4[i] = o;
    }
}

extern "C" void kernel_launch(void* const* d_in, const int* in_sizes, int n_in,
                              void* d_out, int out_size, void* d_ws, size_t ws_size,
                              hipStream_t stream) {
    const float* node_attr  = (const float*)d_in[0];
    const float* edge_attr  = (const float*)d_in[1];
    const float* edge_sh    = (const float*)d_in[2];
    const float* fc_w1      = (const float*)d_in[3];
    const float* fc_b1      = (const float*)d_in[4];
    const float* fc_w2      = (const float*)d_in[5];
    const float* fc_b2      = (const float*)d_in[6];
    const float* mean_shift = (const float*)d_in[7];
    const float* aw         = (const float*)d_in[8];
    const float* ab         = (const float*)d_in[9];
    const int*   edge_index = (const int*)d_in[10];
    float* out = (float*)d_out;

    short* w1f = (short*)((char*)d_ws + W1F_OFF);
    short* w2f = (short*)((char*)d_ws + W2F_OFF);
    float* cnt = (float*)((char*)d_ws + CNT_OFF);

    (void)hipMemsetAsync(d_out, 0, (size_t)N_NODES * 80 * sizeof(float), stream);

    prep_kernel<<<(2048 + 40960 + 255) / 256, 256, 0, stream>>>(fc_w1, fc_w2, w1f, w2f, cnt);
    edge_kernel<<<EBLK, 128, 0, stream>>>(node_attr, edge_attr, edge_sh,
                                          fc_b1, fc_b2, edge_index,
                                          w1f, w2f, out, cnt);
    node_kernel<<<(N_NODES + 255) / 256, 256, 0, stream>>>(node_attr, mean_shift,
                                                           aw, ab, cnt, out);
}